// Round 7
// baseline (1079.383 us; speedup 1.0000x reference)
//
#include <hip/hip_runtime.h>
#include <hip/hip_cooperative_groups.h>
#include <cstdint>
#include <cstddef>

namespace cg = cooperative_groups;

#define CDIV(a,b) (((a)+(b)-1)/(b))

using bf16x8 = __attribute__((ext_vector_type(8))) short;
using f32x4  = __attribute__((ext_vector_type(4))) float;

struct __align__(8) F4 { float x, y, z, w; };
struct __align__(8) F2 { float x, y; };

#define N1C 11264
#define NBC 1024

__device__ __forceinline__ unsigned short sgn_bf16(float s){
  return (s > 0.f) ? 0x3F80u : ((s < 0.f) ? 0xBF80u : 0u);
}

// packed-order -> true column maps (permutation lives ONLY in weight-fill roles)
__device__ __forceinline__ int colX(int k){
  int w = k >> 5, b = k & 31;
  if (w < 16){
    int g = w >> 3, wr = w & 7;
    int j = wr >> 1, half = wr & 1;
    return 256*g + 4*(32*half + b) + j;
  }
  int j = w - 16;
  int c = 512 + 4*b + j;
  return (c < 602) ? c : -1;
}
__device__ __forceinline__ int colH(int k){
  int w = k >> 5, b = k & 31;
  int j = w >> 1, half = w & 1;
  return 4*(32*half + b) + j;
}

struct KParams {
  const float* x; const int* ei1; const int* ei2;
  const float* W1l; const float* W1r; const float* b1;
  const float* W2l; const float* W2r; const float* b2;
  float* out;
  uint32_t* packedX; uint32_t* packedH;
  unsigned short* Sx; float* invdeg;
  unsigned short* bsgn; float* Bcat2;
  float* aL; float* aR; float* a2L; float* a2R;
  unsigned char* mask;
  int* deg1; int* deg2;          // contiguous: deg1[N1C] then deg2[NBC]
  int* rs1; int* cur1; int* esrc1;
  int* rs2; int* cur2; int* esrc2;
  int N0, E1, E2;
};

__global__ __launch_bounds__(256, 4) void mega(KParams P){
  cg::grid_group grid = cg::this_grid();
  __shared__ __align__(16) char smem[33792];
  const int tid  = threadIdx.x;
  const int lane = tid & 63, wid = tid >> 6;
  const int gsz  = (int)gridDim.x;

  // ============ P0: alphas (594) + mask init + zero degs ============
  {
    const int maskBlocks = CDIV(P.N0, 256);
    const int total = 594 + maskBlocks + CDIV(N1C + NBC, 256);
    for (int vb = blockIdx.x; vb < total; vb += gsz){
      if (vb < 594){
        const float* wr; float* dst; int K;
        if (vb < 256){ wr = P.W1l + (size_t)vb*602; dst = P.aL + vb; K = 602; }
        else if (vb < 512){ int q = vb-256; wr = P.W1r + (size_t)q*602; dst = P.aR + q; K = 602; }
        else if (vb < 553){ int q = vb-512; wr = P.W2l + (size_t)q*256; dst = P.a2L + q; K = 256; }
        else { int q = vb-553; wr = P.W2r + (size_t)q*256; dst = P.a2R + q; K = 256; }
        float s = 0.f;
        for (int k = tid; k < K; k += 256) s += fabsf(wr[k]);
        #pragma unroll
        for (int off = 32; off; off >>= 1) s += __shfl_xor(s, off);
        float* red = (float*)smem;
        if (lane == 0) red[wid] = s;
        __syncthreads();
        if (tid == 0) *dst = (red[0]+red[1]+red[2]+red[3]) / (float)K;
        __syncthreads();
      } else if (vb < 594 + maskBlocks){
        int i = (vb-594)*256 + tid;
        if (i < P.N0) P.mask[i] = (i < N1C) ? 1 : 0;
      } else {
        int i = (vb - 594 - maskBlocks)*256 + tid;
        if (i < N1C + NBC) P.deg1[i] = 0;
      }
    }
  }
  __threadfence(); grid.sync();

  // ============ P1: mark+count || bsgn fill || Bcat2 fill ============
  {
    const int cntBlocks = CDIV(P.E1 + P.E2, 256);
    const int total = cntBlocks + 1280 + CDIV(512*41, 256);
    for (int vb = blockIdx.x; vb < total; vb += gsz){
      if (vb < cntBlocks){
        int e = vb*256 + tid;
        if (e < P.E1){
          P.mask[P.ei1[e]] = 1;
          atomicAdd(&P.deg1[P.ei1[P.E1 + e]], 1);
        } else if (e < P.E1 + P.E2){
          int q = e - P.E1;
          atomicAdd(&P.deg2[P.ei2[P.E2 + q]], 1);
        }
      } else if (vb < cntBlocks + 1280){
        int idx = (vb - cntBlocks)*256 + tid;        // exactly 256*1280
        int o = idx / 1280, k = idx - o*1280;
        float v = 0.f;
        if (k < 640){ int c = colX(k);       if (c >= 0) v = P.W1l[(size_t)o*602 + c]; }
        else        { int c = colX(k - 640); if (c >= 0) v = P.W1r[(size_t)o*602 + c]; }
        P.bsgn[idx] = sgn_bf16(v);
      } else {
        int idx = (vb - cntBlocks - 1280)*256 + tid;
        if (idx < 512*41){
          int o = idx % 41, k = idx / 41;
          int c = (k < 256) ? colH(k) : colH(k - 256);
          float w = (k < 256) ? P.W2l[(size_t)o*256 + c] : P.W2r[(size_t)o*256 + c];
          float a = (k < 256) ? P.a2L[o] : P.a2R[o];
          float sg = (w > 0.f) ? 1.f : ((w < 0.f) ? -1.f : 0.f);
          P.Bcat2[idx] = a * sg;
        }
      }
    }
  }
  __threadfence(); grid.sync();

  // ============ P2: masked pack(x) || dual scans ============
  {
    const int packBlocks = CDIV(P.N0, 4);
    const int total = packBlocks + 2;
    for (int vb = blockIdx.x; vb < total; vb += gsz){
      if (vb < packBlocks){
        int row = vb*4 + wid;
        if (row < P.N0 && P.mask[row]){
          const float* xr = P.x + (size_t)row * 602;
          F4 v0 = *(const F4*)&xr[4*lane];
          F4 v1 = *(const F4*)&xr[256 + 4*lane];
          F4 v2 = {0.f,0.f,0.f,0.f};
          if (lane < 22) v2 = *(const F4*)&xr[512 + 4*lane];
          else if (lane == 22){ F2 t = *(const F2*)&xr[600]; v2.x = t.x; v2.y = t.y; }
          float s = v0.x+v0.y+v0.z+v0.w + v1.x+v1.y+v1.z+v1.w + v2.x+v2.y+v2.z+v2.w;
          #pragma unroll
          for (int off = 32; off; off >>= 1) s += __shfl_xor(s, off);
          const float mean = s / 602.f;
          uint32_t wpos[20], wneg[20];
          {
            float d0 = v0.x - mean, d1v = v0.y - mean, d2v = v0.z - mean, d3 = v0.w - mean;
            unsigned long long b0 = __ballot(d0 > 0.f), b1 = __ballot(d1v > 0.f),
                               b2 = __ballot(d2v > 0.f), b3 = __ballot(d3 > 0.f);
            wpos[0]=(uint32_t)b0; wpos[1]=(uint32_t)(b0>>32); wpos[2]=(uint32_t)b1; wpos[3]=(uint32_t)(b1>>32);
            wpos[4]=(uint32_t)b2; wpos[5]=(uint32_t)(b2>>32); wpos[6]=(uint32_t)b3; wpos[7]=(uint32_t)(b3>>32);
            b0 = __ballot(d0 < 0.f); b1 = __ballot(d1v < 0.f); b2 = __ballot(d2v < 0.f); b3 = __ballot(d3 < 0.f);
            wneg[0]=(uint32_t)b0; wneg[1]=(uint32_t)(b0>>32); wneg[2]=(uint32_t)b1; wneg[3]=(uint32_t)(b1>>32);
            wneg[4]=(uint32_t)b2; wneg[5]=(uint32_t)(b2>>32); wneg[6]=(uint32_t)b3; wneg[7]=(uint32_t)(b3>>32);
          }
          {
            float d0 = v1.x - mean, d1v = v1.y - mean, d2v = v1.z - mean, d3 = v1.w - mean;
            unsigned long long b0 = __ballot(d0 > 0.f), b1 = __ballot(d1v > 0.f),
                               b2 = __ballot(d2v > 0.f), b3 = __ballot(d3 > 0.f);
            wpos[8]=(uint32_t)b0; wpos[9]=(uint32_t)(b0>>32); wpos[10]=(uint32_t)b1; wpos[11]=(uint32_t)(b1>>32);
            wpos[12]=(uint32_t)b2; wpos[13]=(uint32_t)(b2>>32); wpos[14]=(uint32_t)b3; wpos[15]=(uint32_t)(b3>>32);
            b0 = __ballot(d0 < 0.f); b1 = __ballot(d1v < 0.f); b2 = __ballot(d2v < 0.f); b3 = __ballot(d3 < 0.f);
            wneg[8]=(uint32_t)b0; wneg[9]=(uint32_t)(b0>>32); wneg[10]=(uint32_t)b1; wneg[11]=(uint32_t)(b1>>32);
            wneg[12]=(uint32_t)b2; wneg[13]=(uint32_t)(b2>>32); wneg[14]=(uint32_t)b3; wneg[15]=(uint32_t)(b3>>32);
          }
          {
            int base = 4*lane;
            float d0 = v2.x - mean, d1v = v2.y - mean, d2v = v2.z - mean, d3 = v2.w - mean;
            wpos[16] = (uint32_t)__ballot((base+0 < 90) && (d0 > 0.f));
            wpos[17] = (uint32_t)__ballot((base+1 < 90) && (d1v > 0.f));
            wpos[18] = (uint32_t)__ballot((base+2 < 90) && (d2v > 0.f));
            wpos[19] = (uint32_t)__ballot((base+3 < 90) && (d3 > 0.f));
            wneg[16] = (uint32_t)__ballot((base+0 < 90) && (d0 < 0.f));
            wneg[17] = (uint32_t)__ballot((base+1 < 90) && (d1v < 0.f));
            wneg[18] = (uint32_t)__ballot((base+2 < 90) && (d2v < 0.f));
            wneg[19] = (uint32_t)__ballot((base+3 < 90) && (d3 < 0.f));
          }
          if (lane == 0){
            uint32_t* pr = P.packedX + (size_t)row * 40;
            #pragma unroll
            for (int q = 0; q < 5; ++q){
              uint4 a; a.x = wpos[4*q]; a.y = wpos[4*q+1]; a.z = wpos[4*q+2]; a.w = wpos[4*q+3];
              *(uint4*)&pr[4*q] = a;
              uint4 b; b.x = wneg[4*q]; b.y = wneg[4*q+1]; b.z = wneg[4*q+2]; b.w = wneg[4*q+3];
              *(uint4*)&pr[20 + 4*q] = b;
            }
          }
        }
      } else {
        int role = vb - packBlocks;
        const int* deg = role ? P.deg2 : P.deg1;
        int* rs  = role ? P.rs2  : P.rs1;
        int* cur = role ? P.cur2 : P.cur1;
        int n    = role ? NBC    : N1C;
        int* partial = (int*)smem;
        int per = CDIV(n, 256);
        int begin = tid*per; if (begin > n) begin = n;
        int end = begin + per; if (end > n) end = n;
        int s = 0;
        for (int i = begin; i < end; ++i) s += deg[i];
        partial[tid] = s;
        __syncthreads();
        for (int off = 1; off < 256; off <<= 1){
          int add = (tid >= off) ? partial[tid-off] : 0;
          __syncthreads();
          partial[tid] += add;
          __syncthreads();
        }
        int prefix = (tid == 0) ? 0 : partial[tid-1];
        for (int i = begin; i < end; ++i){ rs[i] = prefix; cur[i] = prefix; prefix += deg[i]; }
        if (tid == 255) rs[n] = prefix;
        __syncthreads();
      }
    }
  }
  __threadfence(); grid.sync();

  // ============ P3: CSR fill (both) ============
  {
    const int cntBlocks = CDIV(P.E1 + P.E2, 256);
    for (int vb = blockIdx.x; vb < cntBlocks; vb += gsz){
      int e = vb*256 + tid;
      if (e < P.E1){
        int pos = atomicAdd(&P.cur1[P.ei1[P.E1 + e]], 1);
        P.esrc1[pos] = P.ei1[e];
      } else if (e < P.E1 + P.E2){
        int q = e - P.E1;
        int pos = atomicAdd(&P.cur2[P.ei2[P.E2 + q]], 1);
        P.esrc2[pos] = P.ei2[q];
      }
    }
  }
  __threadfence(); grid.sync();

  // ============ P4: layer-1 aggregate (wave per target, 3 edges in flight) ============
  {
    for (int vb = blockIdx.x; vb < N1C/4; vb += gsz){
      int t = vb*4 + wid;
      const int slot = lane / 20;       // 0..2 active; 3 idle
      const int w = lane - slot*20;
      const int s0 = P.rs1[t], s1 = P.rs1[t+1];
      const bool act = slot < 3;
      uint32_t pp[8] = {0,0,0,0,0,0,0,0};
      uint32_t nn[8] = {0,0,0,0,0,0,0,0};
      for (int base = s0; base < s1; base += 3){
        int e = base + slot;
        uint32_t wp = 0, wn = 0;
        if (act && e < s1){
          const uint32_t* pr = P.packedX + (size_t)P.esrc1[e] * 40;
          wp = pr[w]; wn = pr[20 + w];
        }
        #pragma unroll
        for (int b = 0; b < 8; ++b){
          pp[b] += (wp >> b) & 0x01010101u;
          nn[b] += (wn >> b) & 0x01010101u;
        }
      }
      #pragma unroll
      for (int b = 0; b < 8; ++b){
        pp[b] += __shfl(pp[b], lane + 20) + __shfl(pp[b], lane + 40);
        nn[b] += __shfl(nn[b], lane + 20) + __shfl(nn[b], lane + 40);
      }
      if (lane == 0){
        int deg = s1 - s0;
        P.invdeg[t] = 1.f / (float)(deg > 0 ? deg : 1);
      }
      if (lane < 20){
        unsigned short* sr = P.Sx + (size_t)t * 640;
        #pragma unroll
        for (int b = 0; b < 8; ++b){
          #pragma unroll
          for (int k = 0; k < 4; ++k){
            int col = 32*lane + b + 8*k;
            int cnt = (int)((pp[b] >> (8*k)) & 0xFF) - (int)((nn[b] >> (8*k)) & 0xFF);
            float f = (float)cnt;
            sr[col] = (unsigned short)(__float_as_uint(f) >> 16);
          }
        }
      }
    }
  }
  __threadfence(); grid.sync();

  // ============ P5: layer-1 MFMA GEMM (32x256) + fused norm_bin pack ============
  {
    unsigned short (*As)[40] = (unsigned short (*)[40])smem;
    unsigned short (*Bs)[40] = (unsigned short (*)[40])(smem + 32*40*2);
    float (*Hs)[264] = (float (*)[264])smem;
    const int frow = lane & 15, fk = (lane >> 4) * 8;
    const int sRow = tid >> 3, sK = (tid & 7) * 4;
    for (int vb = blockIdx.x; vb < N1C/32; vb += gsz){
      const int m0 = vb * 32;
      f32x4 acc1[2][4], acc2[2][4];
      #pragma unroll
      for (int i = 0; i < 2; ++i)
        #pragma unroll
        for (int j = 0; j < 4; ++j){ f32x4 z = {0.f,0.f,0.f,0.f}; acc1[i][j] = z; acc2[i][j] = z; }
      const unsigned short* SxRow = P.Sx + (size_t)(m0 + sRow) * 640;
      const uint32_t* pxRow = P.packedX + (size_t)(m0 + sRow) * 40;
      const unsigned short* bsgnCol = P.bsgn + (size_t)tid * 1280;

      for (int kc = 0; kc < 640; kc += 32){
        *(uint2*)&As[sRow][sK] = *(const uint2*)&SxRow[kc + sK];
        *(bf16x8*)&Bs[tid][0]  = *(const bf16x8*)&bsgnCol[kc];
        *(bf16x8*)&Bs[tid][8]  = *(const bf16x8*)&bsgnCol[kc + 8];
        *(bf16x8*)&Bs[tid][16] = *(const bf16x8*)&bsgnCol[kc + 16];
        *(bf16x8*)&Bs[tid][24] = *(const bf16x8*)&bsgnCol[kc + 24];
        __syncthreads();
        bf16x8 a0 = *(bf16x8*)&As[frow][fk];
        bf16x8 a1 = *(bf16x8*)&As[16 + frow][fk];
        #pragma unroll
        for (int nf = 0; nf < 4; ++nf){
          bf16x8 b = *(bf16x8*)&Bs[wid*64 + nf*16 + frow][fk];
          acc1[0][nf] = __builtin_amdgcn_mfma_f32_16x16x32_bf16(a0, b, acc1[0][nf], 0, 0, 0);
          acc1[1][nf] = __builtin_amdgcn_mfma_f32_16x16x32_bf16(a1, b, acc1[1][nf], 0, 0, 0);
        }
        __syncthreads();
      }
      for (int kc = 0; kc < 640; kc += 32){
        int w = kc >> 5;
        {
          uint32_t wp = pxRow[w];
          uint32_t wq = pxRow[20 + w];
          union { unsigned short u[4]; uint2 v; } tmp;
          #pragma unroll
          for (int j = 0; j < 4; ++j){
            int b_ = sK + j;
            tmp.u[j] = ((wp >> b_) & 1) ? 0x3F80u : (((wq >> b_) & 1) ? 0xBF80u : 0u);
          }
          *(uint2*)&As[sRow][sK] = tmp.v;
        }
        *(bf16x8*)&Bs[tid][0]  = *(const bf16x8*)&bsgnCol[640 + kc];
        *(bf16x8*)&Bs[tid][8]  = *(const bf16x8*)&bsgnCol[640 + kc + 8];
        *(bf16x8*)&Bs[tid][16] = *(const bf16x8*)&bsgnCol[640 + kc + 16];
        *(bf16x8*)&Bs[tid][24] = *(const bf16x8*)&bsgnCol[640 + kc + 24];
        __syncthreads();
        bf16x8 a0 = *(bf16x8*)&As[frow][fk];
        bf16x8 a1 = *(bf16x8*)&As[16 + frow][fk];
        #pragma unroll
        for (int nf = 0; nf < 4; ++nf){
          bf16x8 b = *(bf16x8*)&Bs[wid*64 + nf*16 + frow][fk];
          acc2[0][nf] = __builtin_amdgcn_mfma_f32_16x16x32_bf16(a0, b, acc2[0][nf], 0, 0, 0);
          acc2[1][nf] = __builtin_amdgcn_mfma_f32_16x16x32_bf16(a1, b, acc2[1][nf], 0, 0, 0);
        }
        __syncthreads();
      }

      #pragma unroll
      for (int nf = 0; nf < 4; ++nf){
        int gc = wid*64 + nf*16 + frow;
        float al = P.aL[gc], ar = P.aR[gc], bb = P.b1[gc];
        #pragma unroll
        for (int mf = 0; mf < 2; ++mf){
          #pragma unroll
          for (int reg = 0; reg < 4; ++reg){
            int lr = mf*16 + (lane >> 4)*4 + reg;
            float v = P.invdeg[m0 + lr]*al*acc1[mf][nf][reg] + ar*acc2[mf][nf][reg] + bb;
            Hs[lr][gc] = fmaxf(v, 0.f);
          }
        }
      }
      __syncthreads();

      for (int r = 0; r < 8; ++r){
        int row = wid*8 + r;
        float4 v = *(const float4*)&Hs[row][4*lane];
        float s = v.x + v.y + v.z + v.w;
        #pragma unroll
        for (int off = 32; off; off >>= 1) s += __shfl_xor(s, off);
        float mean = s * (1.f/256.f);
        float d0 = v.x - mean, d1v = v.y - mean, d2v = v.z - mean, d3 = v.w - mean;
        unsigned long long b0 = __ballot(d0 > 0.f), b1 = __ballot(d1v > 0.f),
                           b2 = __ballot(d2v > 0.f), b3 = __ballot(d3 > 0.f);
        uint32_t wpos[8], wneg[8];
        wpos[0]=(uint32_t)b0; wpos[1]=(uint32_t)(b0>>32); wpos[2]=(uint32_t)b1; wpos[3]=(uint32_t)(b1>>32);
        wpos[4]=(uint32_t)b2; wpos[5]=(uint32_t)(b2>>32); wpos[6]=(uint32_t)b3; wpos[7]=(uint32_t)(b3>>32);
        b0 = __ballot(d0 < 0.f); b1 = __ballot(d1v < 0.f); b2 = __ballot(d2v < 0.f); b3 = __ballot(d3 < 0.f);
        wneg[0]=(uint32_t)b0; wneg[1]=(uint32_t)(b0>>32); wneg[2]=(uint32_t)b1; wneg[3]=(uint32_t)(b1>>32);
        wneg[4]=(uint32_t)b2; wneg[5]=(uint32_t)(b2>>32); wneg[6]=(uint32_t)b3; wneg[7]=(uint32_t)(b3>>32);
        if (lane == 0){
          uint32_t* pr = P.packedH + (size_t)(m0 + row) * 16;
          *(uint4*)&pr[0]  = make_uint4(wpos[0], wpos[1], wpos[2], wpos[3]);
          *(uint4*)&pr[4]  = make_uint4(wpos[4], wpos[5], wpos[6], wpos[7]);
          *(uint4*)&pr[8]  = make_uint4(wneg[0], wneg[1], wneg[2], wneg[3]);
          *(uint4*)&pr[12] = make_uint4(wneg[4], wneg[5], wneg[6], wneg[7]);
        }
      }
      __syncthreads();
    }
  }
  __threadfence(); grid.sync();

  // ============ P6: layer-2 aggregate + GEMM + log_softmax (wave per target) ============
  {
    float (*av)[512] = (float (*)[512])smem;   // 4 waves x 512 f32 = 8 KB
    for (int vb = blockIdx.x; vb < NBC/4; vb += gsz){
      int t = vb*4 + wid;
      float* avw = av[wid];
      const int slot = lane >> 3, w = lane & 7;
      const int s0 = P.rs2[t], s1 = P.rs2[t+1];
      uint32_t pp[8] = {0,0,0,0,0,0,0,0};
      uint32_t nn[8] = {0,0,0,0,0,0,0,0};
      for (int base = s0; base < s1; base += 8){
        int e = base + slot;
        uint32_t wp = 0, wn = 0;
        if (e < s1){
          const uint32_t* pr = P.packedH + (size_t)P.esrc2[e] * 16;
          wp = pr[w]; wn = pr[8 + w];
        }
        #pragma unroll
        for (int b = 0; b < 8; ++b){
          pp[b] += (wp >> b) & 0x01010101u;
          nn[b] += (wn >> b) & 0x01010101u;
        }
      }
      #pragma unroll
      for (int b = 0; b < 8; ++b){
        pp[b] += __shfl_xor(pp[b], 8);  pp[b] += __shfl_xor(pp[b], 16);  pp[b] += __shfl_xor(pp[b], 32);
        nn[b] += __shfl_xor(nn[b], 8);  nn[b] += __shfl_xor(nn[b], 16);  nn[b] += __shfl_xor(nn[b], 32);
      }
      int deg = s1 - s0;
      float inv = 1.f / (float)(deg > 0 ? deg : 1);
      if (lane < 8){
        #pragma unroll
        for (int b = 0; b < 8; ++b){
          #pragma unroll
          for (int k = 0; k < 4; ++k){
            int col = 32*lane + b + 8*k;
            int cnt = (int)((pp[b] >> (8*k)) & 0xFF) - (int)((nn[b] >> (8*k)) & 0xFF);
            avw[col] = (float)cnt * inv;
          }
        }
      }
      const uint32_t* pr = P.packedH + (size_t)t * 16;
      for (int k = lane; k < 256; k += 64){
        int wq = k >> 5, b = k & 31;
        avw[256 + k] = (float)((pr[wq] >> b) & 1) - (float)((pr[8 + wq] >> b) & 1);
      }
      __syncthreads();
      bool activeO = lane < 41;
      float acc = activeO ? P.b2[lane] : 0.f;
      for (int k = 0; k < 512; ++k){
        float bw = activeO ? P.Bcat2[k*41 + lane] : 0.f;
        acc += avw[k] * bw;
      }
      float v = activeO ? acc : -INFINITY;
      float m = v;
      #pragma unroll
      for (int off = 32; off; off >>= 1) m = fmaxf(m, __shfl_xor(m, off));
      float e = activeO ? expf(v - m) : 0.f;
      float ssum = e;
      #pragma unroll
      for (int off = 32; off; off >>= 1) ssum += __shfl_xor(ssum, off);
      if (activeO) P.out[(size_t)t*41 + lane] = v - m - logf(ssum);
      __syncthreads();
    }
  }
}

extern "C" void kernel_launch(void* const* d_in, const int* in_sizes, int n_in,
                              void* d_out, int out_size, void* d_ws, size_t ws_size,
                              hipStream_t stream){
  (void)n_in; (void)out_size; (void)ws_size;
  const int FIN = 602;
  const int N0 = in_sizes[0] / FIN;
  const int E1 = in_sizes[1] / 2;
  const int E2 = in_sizes[2] / 2;

  char* wsb = (char*)d_ws;
  size_t off = 0;
  auto carve = [&](size_t bytes)->void*{
    void* p = wsb + off;
    off = (off + bytes + 255) & ~(size_t)255;
    return p;
  };
  uint32_t* packedX = (uint32_t*)carve((size_t)N0*40*4);
  uint32_t* packedH = (uint32_t*)carve((size_t)N1C*16*4);
  unsigned short* Sx = (unsigned short*)carve((size_t)N1C*640*2);
  float* invdeg = (float*)carve((size_t)N1C*4);
  unsigned short* bsgn = (unsigned short*)carve((size_t)256*1280*2);
  float* Bcat2 = (float*)carve((size_t)512*41*4);
  float* aL  = (float*)carve(256*4);
  float* aR  = (float*)carve(256*4);
  float* a2L = (float*)carve(64*4);
  float* a2R = (float*)carve(64*4);
  unsigned char* mask = (unsigned char*)carve((size_t)N0);
  int* degB  = (int*)carve((size_t)(N1C+NBC)*4);
  int* rs1   = (int*)carve((size_t)(N1C+1)*4);
  int* cur1  = (int*)carve((size_t)N1C*4);
  int* esrc1 = (int*)carve((size_t)E1*4);
  int* rs2   = (int*)carve((size_t)(NBC+1)*4);
  int* cur2  = (int*)carve((size_t)NBC*4);
  int* esrc2 = (int*)carve((size_t)E2*4);

  KParams p;
  p.x = (const float*)d_in[0];
  p.ei1 = (const int*)d_in[1];
  p.ei2 = (const int*)d_in[2];
  p.W1l = (const float*)d_in[5];
  p.W1r = (const float*)d_in[6];
  p.b1  = (const float*)d_in[7];
  p.W2l = (const float*)d_in[8];
  p.W2r = (const float*)d_in[9];
  p.b2  = (const float*)d_in[10];
  p.out = (float*)d_out;
  p.packedX = packedX; p.packedH = packedH;
  p.Sx = Sx; p.invdeg = invdeg;
  p.bsgn = bsgn; p.Bcat2 = Bcat2;
  p.aL = aL; p.aR = aR; p.a2L = a2L; p.a2R = a2R;
  p.mask = mask;
  p.deg1 = degB; p.deg2 = degB + N1C;
  p.rs1 = rs1; p.cur1 = cur1; p.esrc1 = esrc1;
  p.rs2 = rs2; p.cur2 = cur2; p.esrc2 = esrc2;
  p.N0 = N0; p.E1 = E1; p.E2 = E2;

  int nb = 0;
  hipOccupancyMaxActiveBlocksPerMultiprocessor(&nb, mega, 256, 0);
  if (nb < 1) nb = 1;
  if (nb > 4) nb = 4;
  int grid = nb * 256;        // 256 CUs on MI355X

  void* args[] = { (void*)&p };
  hipLaunchCooperativeKernel((void*)mega, dim3(grid), dim3(256), args, 0, stream);
}

// Round 8
// 270.692 us; speedup vs baseline: 3.9875x; 3.9875x over previous
//
#include <hip/hip_runtime.h>
#include <hip/hip_bf16.h>
#include <cstdint>
#include <cstddef>

#define CDIV(a,b) (((a)+(b)-1)/(b))

using bf16x8 = __attribute__((ext_vector_type(8))) short;
using f32x4  = __attribute__((ext_vector_type(4))) float;

struct __align__(8) F4 { float x, y, z, w; };
struct __align__(8) F2 { float x, y; };

__device__ __forceinline__ unsigned short sgn_bf16(float s){
  return (s > 0.f) ? 0x3F80u : ((s < 0.f) ? 0xBF80u : 0u);
}

// packed-order -> true column maps (permutation lives ONLY in weight-fill kernels)
__device__ __forceinline__ int colX(int k){
  int w = k >> 5, b = k & 31;
  if (w < 16){
    int g = w >> 3, wr = w & 7;
    int j = wr >> 1, half = wr & 1;
    return 256*g + 4*(32*half + b) + j;
  }
  int j = w - 16;
  int c = 512 + 4*b + j;
  return (c < 602) ? c : -1;
}
__device__ __forceinline__ int colH(int k){
  int w = k >> 5, b = k & 31;
  int j = w >> 1, half = w & 1;
  return 4*(32*half + b) + j;
}

// pack one 602-col row already loaded into v0,v1,v2 (cols 4l, 256+4l, 512+4l)
__device__ __forceinline__ void pack_row602(F4 v0, F4 v1, F4 v2, int lane, uint32_t* pr){
  float s = v0.x+v0.y+v0.z+v0.w + v1.x+v1.y+v1.z+v1.w + v2.x+v2.y+v2.z+v2.w;
  #pragma unroll
  for (int off = 32; off; off >>= 1) s += __shfl_xor(s, off);
  const float mean = s / 602.f;
  uint32_t wpos[20], wneg[20];
  {
    float d0 = v0.x - mean, d1v = v0.y - mean, d2v = v0.z - mean, d3 = v0.w - mean;
    unsigned long long b0 = __ballot(d0 > 0.f), b1 = __ballot(d1v > 0.f),
                       b2 = __ballot(d2v > 0.f), b3 = __ballot(d3 > 0.f);
    wpos[0]=(uint32_t)b0; wpos[1]=(uint32_t)(b0>>32); wpos[2]=(uint32_t)b1; wpos[3]=(uint32_t)(b1>>32);
    wpos[4]=(uint32_t)b2; wpos[5]=(uint32_t)(b2>>32); wpos[6]=(uint32_t)b3; wpos[7]=(uint32_t)(b3>>32);
    b0 = __ballot(d0 < 0.f); b1 = __ballot(d1v < 0.f); b2 = __ballot(d2v < 0.f); b3 = __ballot(d3 < 0.f);
    wneg[0]=(uint32_t)b0; wneg[1]=(uint32_t)(b0>>32); wneg[2]=(uint32_t)b1; wneg[3]=(uint32_t)(b1>>32);
    wneg[4]=(uint32_t)b2; wneg[5]=(uint32_t)(b2>>32); wneg[6]=(uint32_t)b3; wneg[7]=(uint32_t)(b3>>32);
  }
  {
    float d0 = v1.x - mean, d1v = v1.y - mean, d2v = v1.z - mean, d3 = v1.w - mean;
    unsigned long long b0 = __ballot(d0 > 0.f), b1 = __ballot(d1v > 0.f),
                       b2 = __ballot(d2v > 0.f), b3 = __ballot(d3 > 0.f);
    wpos[8]=(uint32_t)b0; wpos[9]=(uint32_t)(b0>>32); wpos[10]=(uint32_t)b1; wpos[11]=(uint32_t)(b1>>32);
    wpos[12]=(uint32_t)b2; wpos[13]=(uint32_t)(b2>>32); wpos[14]=(uint32_t)b3; wpos[15]=(uint32_t)(b3>>32);
    b0 = __ballot(d0 < 0.f); b1 = __ballot(d1v < 0.f); b2 = __ballot(d2v < 0.f); b3 = __ballot(d3 < 0.f);
    wneg[8]=(uint32_t)b0; wneg[9]=(uint32_t)(b0>>32); wneg[10]=(uint32_t)b1; wneg[11]=(uint32_t)(b1>>32);
    wneg[12]=(uint32_t)b2; wneg[13]=(uint32_t)(b2>>32); wneg[14]=(uint32_t)b3; wneg[15]=(uint32_t)(b3>>32);
  }
  {
    int base = 4*lane;
    float d0 = v2.x - mean, d1v = v2.y - mean, d2v = v2.z - mean, d3 = v2.w - mean;
    wpos[16] = (uint32_t)__ballot((base+0 < 90) && (d0 > 0.f));
    wpos[17] = (uint32_t)__ballot((base+1 < 90) && (d1v > 0.f));
    wpos[18] = (uint32_t)__ballot((base+2 < 90) && (d2v > 0.f));
    wpos[19] = (uint32_t)__ballot((base+3 < 90) && (d3 > 0.f));
    wneg[16] = (uint32_t)__ballot((base+0 < 90) && (d0 < 0.f));
    wneg[17] = (uint32_t)__ballot((base+1 < 90) && (d1v < 0.f));
    wneg[18] = (uint32_t)__ballot((base+2 < 90) && (d2v < 0.f));
    wneg[19] = (uint32_t)__ballot((base+3 < 90) && (d3 < 0.f));
  }
  if (lane == 0){
    #pragma unroll
    for (int q = 0; q < 5; ++q){
      uint4 a; a.x = wpos[4*q]; a.y = wpos[4*q+1]; a.z = wpos[4*q+2]; a.w = wpos[4*q+3];
      *(uint4*)&pr[4*q] = a;
      uint4 b; b.x = wneg[4*q]; b.y = wneg[4*q+1]; b.z = wneg[4*q+2]; b.w = wneg[4*q+3];
      *(uint4*)&pr[20 + 4*q] = b;
    }
  }
}

// ---------------- L0: alphas + zero degs + bsgn + mask init ----------------
__global__ void prep_all(const float* __restrict__ W1l, const float* __restrict__ W1r,
                         const float* __restrict__ W2l, const float* __restrict__ W2r,
                         float* __restrict__ aL, float* __restrict__ aR,
                         float* __restrict__ a2L, float* __restrict__ a2R,
                         int* __restrict__ degB, int ndeg,
                         unsigned short* __restrict__ bsgn,
                         unsigned char* __restrict__ mask, int n0, int n1){
  int r = blockIdx.x;
  if (r < 594){
    const float* wr; float* dst; int K;
    if (r < 256){ wr = W1l + (size_t)r*602; dst = aL + r; K = 602; }
    else if (r < 512){ int q = r-256; wr = W1r + (size_t)q*602; dst = aR + q; K = 602; }
    else if (r < 553){ int q = r-512; wr = W2l + (size_t)q*256; dst = a2L + q; K = 256; }
    else { int q = r-553; wr = W2r + (size_t)q*256; dst = a2R + q; K = 256; }
    float s = 0.f;
    for (int k = threadIdx.x; k < K; k += blockDim.x) s += fabsf(wr[k]);
    #pragma unroll
    for (int off = 32; off; off >>= 1) s += __shfl_xor(s, off);
    __shared__ float red[4];
    int wid = threadIdx.x >> 6, lane = threadIdx.x & 63;
    if (lane == 0) red[wid] = s;
    __syncthreads();
    if (threadIdx.x == 0) *dst = (red[0]+red[1]+red[2]+red[3]) / (float)K;
  } else if (r < 642){
    int i = (r - 594)*256 + threadIdx.x;
    if (i < ndeg) degB[i] = 0;
  } else if (r < 1922){
    int idx = (r - 642)*256 + threadIdx.x;
    if (idx < 256*1280){
      int o = idx / 1280, k = idx - o*1280;
      float v = 0.f;
      if (k < 640){ int c = colX(k);       if (c >= 0) v = W1l[(size_t)o*602 + c]; }
      else        { int c = colX(k - 640); if (c >= 0) v = W1r[(size_t)o*602 + c]; }
      bsgn[idx] = sgn_bf16(v);
    }
  } else {
    int i = (r - 1922)*256 + threadIdx.x;
    if (i < n0) mask[i] = (i < n1) ? 1 : 0;
  }
}

// ---------------- L0.5: mark used src rows + count degrees ----------------
__global__ void mark_count(const int* __restrict__ s1, const int* __restrict__ d1, int E1,
                           unsigned char* __restrict__ mask, int* __restrict__ deg1,
                           const int* __restrict__ d2, int E2, int* __restrict__ deg2){
  int e = blockIdx.x*blockDim.x + threadIdx.x;
  if (e < E1){
    mask[s1[e]] = 1;
    atomicAdd(&deg1[d1[e]], 1);
  } else if (e < E1 + E2){
    atomicAdd(&deg2[d2[e - E1]], 1);
  }
}

// ---------------- L1: masked pack(x) 2 rows/wave + dual scans + Bcat2 ----------------
__global__ void pack_scan_bcat(const float* __restrict__ X, uint32_t* __restrict__ P, int nrows,
                               const unsigned char* __restrict__ mask, int packBlocks,
                               const int* __restrict__ deg1, int* __restrict__ rs1, int* __restrict__ cur1, int n1c,
                               const int* __restrict__ deg2, int* __restrict__ rs2, int* __restrict__ cur2, int n2c,
                               const float* __restrict__ W2l, const float* __restrict__ W2r,
                               const float* __restrict__ a2L, const float* __restrict__ a2R,
                               float* __restrict__ Bcat2){
  __shared__ int partial[256];
  const int bid = blockIdx.x;
  if (bid >= packBlocks){
    int role = bid - packBlocks;
    if (role < 2){
      const int* deg = role ? deg2 : deg1;
      int* rs  = role ? rs2  : rs1;
      int* cur = role ? cur2 : cur1;
      int n    = role ? n2c  : n1c;
      int tid = threadIdx.x;
      int per = CDIV(n, 256);
      int begin = tid*per; if (begin > n) begin = n;
      int end = begin + per; if (end > n) end = n;
      int s = 0;
      for (int i = begin; i < end; ++i) s += deg[i];
      partial[tid] = s;
      __syncthreads();
      for (int off = 1; off < 256; off <<= 1){
        int add = (tid >= off) ? partial[tid-off] : 0;
        __syncthreads();
        partial[tid] += add;
        __syncthreads();
      }
      int prefix = (tid == 0) ? 0 : partial[tid-1];
      for (int i = begin; i < end; ++i){ rs[i] = prefix; cur[i] = prefix; prefix += deg[i]; }
      if (tid == 255) rs[n] = prefix;
    } else {
      int idx = (role - 2)*256 + threadIdx.x;
      if (idx < 512*41){
        int o = idx % 41, k = idx / 41;
        int c = (k < 256) ? colH(k) : colH(k - 256);
        float w = (k < 256) ? W2l[(size_t)o*256 + c] : W2r[(size_t)o*256 + c];
        float a = (k < 256) ? a2L[o] : a2R[o];
        float sg = (w > 0.f) ? 1.f : ((w < 0.f) ? -1.f : 0.f);
        Bcat2[idx] = a * sg;
      }
    }
    return;
  }
  // ---- pack role: 2 rows per wave (double MLP: both rows' loads issued before use) ----
  const int rp = bid*4 + (threadIdx.x >> 6);
  const int lane = threadIdx.x & 63;
  const int rowA = rp*2, rowB = rp*2 + 1;
  if (rowA >= nrows) return;
  const bool mA = mask[rowA] != 0;
  const bool mB = (rowB < nrows) && (mask[rowB] != 0);
  if (!mA && !mB) return;
  F4 a0 = {0.f,0.f,0.f,0.f}, a1 = a0, a2 = a0;
  F4 c0 = a0, c1 = a0, c2 = a0;
  const float* xa = X + (size_t)rowA * 602;
  const float* xb = X + (size_t)rowB * 602;
  if (mA){
    a0 = *(const F4*)&xa[4*lane];
    a1 = *(const F4*)&xa[256 + 4*lane];
    if (lane < 22) a2 = *(const F4*)&xa[512 + 4*lane];
    else if (lane == 22){ F2 t = *(const F2*)&xa[600]; a2.x = t.x; a2.y = t.y; }
  }
  if (mB){
    c0 = *(const F4*)&xb[4*lane];
    c1 = *(const F4*)&xb[256 + 4*lane];
    if (lane < 22) c2 = *(const F4*)&xb[512 + 4*lane];
    else if (lane == 22){ F2 t = *(const F2*)&xb[600]; c2.x = t.x; c2.y = t.y; }
  }
  if (mA) pack_row602(a0, a1, a2, lane, P + (size_t)rowA * 40);
  if (mB) pack_row602(c0, c1, c2, lane, P + (size_t)rowB * 40);
}

// ---------------- L2: CSR fill (both) ----------------
__global__ void fill_both(const int* __restrict__ s1, const int* __restrict__ d1, int E1,
                          int* __restrict__ cur1, int* __restrict__ esrc1,
                          const int* __restrict__ s2, const int* __restrict__ d2, int E2,
                          int* __restrict__ cur2, int* __restrict__ esrc2){
  int e = blockIdx.x*blockDim.x + threadIdx.x;
  if (e < E1){
    int p = atomicAdd(&cur1[d1[e]], 1);
    esrc1[p] = s1[e];
  } else if (e < E1 + E2){
    int q = e - E1;
    int p = atomicAdd(&cur2[d2[q]], 1);
    esrc2[p] = s2[q];
  }
}

// ---------------- L3: aggregate layer-1, 3 edges in flight (lanes = slot*20+w) ----------------
__global__ void aggregate_v3(const uint32_t* __restrict__ packed,
                             const int* __restrict__ rs, const int* __restrict__ esrc,
                             unsigned short* __restrict__ S, float* __restrict__ invdeg){
  const int t = blockIdx.x;
  const int lane = threadIdx.x;     // 64
  const int slot = lane / 20;       // 0..2 active, 3 = idle (lanes 60..63)
  const int w = lane - slot*20;
  const int s0 = rs[t], s1 = rs[t+1];
  const bool active = slot < 3;
  uint32_t p[8] = {0,0,0,0,0,0,0,0};
  uint32_t n[8] = {0,0,0,0,0,0,0,0};
  for (int base = s0; base < s1; base += 3){
    int e = base + slot;
    uint32_t wp = 0, wn = 0;
    if (active && e < s1){
      const uint32_t* pr = packed + (size_t)esrc[e] * 40;
      wp = pr[w];
      wn = pr[20 + w];
    }
    #pragma unroll
    for (int b = 0; b < 8; ++b){
      p[b] += (wp >> b) & 0x01010101u;
      n[b] += (wn >> b) & 0x01010101u;
    }
  }
  #pragma unroll
  for (int b = 0; b < 8; ++b){
    p[b] += __shfl(p[b], lane + 20) + __shfl(p[b], lane + 40);
    n[b] += __shfl(n[b], lane + 20) + __shfl(n[b], lane + 40);
  }
  if (lane == 0){
    int deg = s1 - s0;
    invdeg[t] = 1.f / (float)(deg > 0 ? deg : 1);
  }
  if (lane < 20){
    unsigned short* sr = S + (size_t)t * 640;
    #pragma unroll
    for (int b = 0; b < 8; ++b){
      #pragma unroll
      for (int k = 0; k < 4; ++k){
        int col = 32*lane + b + 8*k;
        int cnt = (int)((p[b] >> (8*k)) & 0xFF) - (int)((n[b] >> (8*k)) & 0xFF);
        float f = (float)cnt;
        sr[col] = (unsigned short)(__float_as_uint(f) >> 16);
      }
    }
  }
}

// ---------------- L4: layer-1 MFMA GEMM (32x256 tile) + fused norm_bin pack ----------------
__global__ __launch_bounds__(256) void gemm1_fused(
    const unsigned short* __restrict__ Sx, const uint32_t* __restrict__ packedX,
    const unsigned short* __restrict__ bsgn, const float* __restrict__ invdeg,
    const float* __restrict__ aL, const float* __restrict__ aR,
    const float* __restrict__ bias, uint32_t* __restrict__ packedH){
  __shared__ __align__(16) char smem[33792];
  unsigned short (*As)[40] = (unsigned short (*)[40])smem;
  unsigned short (*Bs)[40] = (unsigned short (*)[40])(smem + 32*40*2);
  float (*Hs)[264] = (float (*)[264])smem;

  const int tid = threadIdx.x;
  const int lane = tid & 63, wid = tid >> 6;
  const int m0 = blockIdx.x * 32;
  const int frow = lane & 15, fk = (lane >> 4) * 8;
  const int sRow = tid >> 3, sK = (tid & 7) * 4;

  f32x4 acc1[2][4], acc2[2][4];
  #pragma unroll
  for (int i = 0; i < 2; ++i)
    #pragma unroll
    for (int j = 0; j < 4; ++j){ f32x4 z = {0.f,0.f,0.f,0.f}; acc1[i][j] = z; acc2[i][j] = z; }

  const unsigned short* SxRow = Sx + (size_t)(m0 + sRow) * 640;
  const uint32_t* pxRow = packedX + (size_t)(m0 + sRow) * 40;
  const unsigned short* bsgnCol = bsgn + (size_t)tid * 1280;

  for (int kc = 0; kc < 640; kc += 32){
    *(uint2*)&As[sRow][sK] = *(const uint2*)&SxRow[kc + sK];
    *(bf16x8*)&Bs[tid][0]  = *(const bf16x8*)&bsgnCol[kc];
    *(bf16x8*)&Bs[tid][8]  = *(const bf16x8*)&bsgnCol[kc + 8];
    *(bf16x8*)&Bs[tid][16] = *(const bf16x8*)&bsgnCol[kc + 16];
    *(bf16x8*)&Bs[tid][24] = *(const bf16x8*)&bsgnCol[kc + 24];
    __syncthreads();
    bf16x8 a0 = *(bf16x8*)&As[frow][fk];
    bf16x8 a1 = *(bf16x8*)&As[16 + frow][fk];
    #pragma unroll
    for (int nf = 0; nf < 4; ++nf){
      bf16x8 b = *(bf16x8*)&Bs[wid*64 + nf*16 + frow][fk];
      acc1[0][nf] = __builtin_amdgcn_mfma_f32_16x16x32_bf16(a0, b, acc1[0][nf], 0, 0, 0);
      acc1[1][nf] = __builtin_amdgcn_mfma_f32_16x16x32_bf16(a1, b, acc1[1][nf], 0, 0, 0);
    }
    __syncthreads();
  }
  for (int kc = 0; kc < 640; kc += 32){
    int w = kc >> 5;
    {
      uint32_t wp = pxRow[w];
      uint32_t wq = pxRow[20 + w];
      union { unsigned short u[4]; uint2 v; } tmp;
      #pragma unroll
      for (int j = 0; j < 4; ++j){
        int b_ = sK + j;
        tmp.u[j] = ((wp >> b_) & 1) ? 0x3F80u : (((wq >> b_) & 1) ? 0xBF80u : 0u);
      }
      *(uint2*)&As[sRow][sK] = tmp.v;
    }
    *(bf16x8*)&Bs[tid][0]  = *(const bf16x8*)&bsgnCol[640 + kc];
    *(bf16x8*)&Bs[tid][8]  = *(const bf16x8*)&bsgnCol[640 + kc + 8];
    *(bf16x8*)&Bs[tid][16] = *(const bf16x8*)&bsgnCol[640 + kc + 16];
    *(bf16x8*)&Bs[tid][24] = *(const bf16x8*)&bsgnCol[640 + kc + 24];
    __syncthreads();
    bf16x8 a0 = *(bf16x8*)&As[frow][fk];
    bf16x8 a1 = *(bf16x8*)&As[16 + frow][fk];
    #pragma unroll
    for (int nf = 0; nf < 4; ++nf){
      bf16x8 b = *(bf16x8*)&Bs[wid*64 + nf*16 + frow][fk];
      acc2[0][nf] = __builtin_amdgcn_mfma_f32_16x16x32_bf16(a0, b, acc2[0][nf], 0, 0, 0);
      acc2[1][nf] = __builtin_amdgcn_mfma_f32_16x16x32_bf16(a1, b, acc2[1][nf], 0, 0, 0);
    }
    __syncthreads();
  }

  #pragma unroll
  for (int nf = 0; nf < 4; ++nf){
    int gc = wid*64 + nf*16 + frow;
    float al = aL[gc], ar = aR[gc], bb = bias[gc];
    #pragma unroll
    for (int mf = 0; mf < 2; ++mf){
      #pragma unroll
      for (int reg = 0; reg < 4; ++reg){
        int lr = mf*16 + (lane >> 4)*4 + reg;
        float v = invdeg[m0 + lr]*al*acc1[mf][nf][reg] + ar*acc2[mf][nf][reg] + bb;
        Hs[lr][gc] = fmaxf(v, 0.f);
      }
    }
  }
  __syncthreads();

  for (int r = 0; r < 8; ++r){
    int row = wid*8 + r;
    float4 v = *(const float4*)&Hs[row][4*lane];
    float s = v.x + v.y + v.z + v.w;
    #pragma unroll
    for (int off = 32; off; off >>= 1) s += __shfl_xor(s, off);
    float mean = s * (1.f/256.f);
    float d0 = v.x - mean, d1v = v.y - mean, d2v = v.z - mean, d3 = v.w - mean;
    unsigned long long b0 = __ballot(d0 > 0.f), b1 = __ballot(d1v > 0.f),
                       b2 = __ballot(d2v > 0.f), b3 = __ballot(d3 > 0.f);
    uint32_t wpos[8], wneg[8];
    wpos[0]=(uint32_t)b0; wpos[1]=(uint32_t)(b0>>32); wpos[2]=(uint32_t)b1; wpos[3]=(uint32_t)(b1>>32);
    wpos[4]=(uint32_t)b2; wpos[5]=(uint32_t)(b2>>32); wpos[6]=(uint32_t)b3; wpos[7]=(uint32_t)(b3>>32);
    b0 = __ballot(d0 < 0.f); b1 = __ballot(d1v < 0.f); b2 = __ballot(d2v < 0.f); b3 = __ballot(d3 < 0.f);
    wneg[0]=(uint32_t)b0; wneg[1]=(uint32_t)(b0>>32); wneg[2]=(uint32_t)b1; wneg[3]=(uint32_t)(b1>>32);
    wneg[4]=(uint32_t)b2; wneg[5]=(uint32_t)(b2>>32); wneg[6]=(uint32_t)b3; wneg[7]=(uint32_t)(b3>>32);
    if (lane == 0){
      uint32_t* pr = packedH + (size_t)(m0 + row) * 16;
      *(uint4*)&pr[0]  = make_uint4(wpos[0], wpos[1], wpos[2], wpos[3]);
      *(uint4*)&pr[4]  = make_uint4(wpos[4], wpos[5], wpos[6], wpos[7]);
      *(uint4*)&pr[8]  = make_uint4(wneg[0], wneg[1], wneg[2], wneg[3]);
      *(uint4*)&pr[12] = make_uint4(wneg[4], wneg[5], wneg[6], wneg[7]);
    }
  }
}

// ---------------- L5: fused layer-2 aggregate (8 edges in flight) + GEMM + log_softmax ----------------
__global__ void agg_gemm2(const uint32_t* __restrict__ packedH,
                          const int* __restrict__ rs, const int* __restrict__ esrc,
                          const float* __restrict__ Bcat2, const float* __restrict__ bias,
                          float* __restrict__ out){
  const int t = blockIdx.x;
  const int lane = threadIdx.x;   // 64
  const int slot = lane >> 3, w = lane & 7;
  __shared__ float av[512];
  const int s0 = rs[t], s1 = rs[t+1];
  uint32_t p[8] = {0,0,0,0,0,0,0,0};
  uint32_t n[8] = {0,0,0,0,0,0,0,0};
  for (int base = s0; base < s1; base += 8){
    int e = base + slot;
    uint32_t wp = 0, wn = 0;
    if (e < s1){
      const uint32_t* pr = packedH + (size_t)esrc[e] * 16;
      wp = pr[w];
      wn = pr[8 + w];
    }
    #pragma unroll
    for (int b = 0; b < 8; ++b){
      p[b] += (wp >> b) & 0x01010101u;
      n[b] += (wn >> b) & 0x01010101u;
    }
  }
  #pragma unroll
  for (int b = 0; b < 8; ++b){
    p[b] += __shfl_xor(p[b], 8);  p[b] += __shfl_xor(p[b], 16);  p[b] += __shfl_xor(p[b], 32);
    n[b] += __shfl_xor(n[b], 8);  n[b] += __shfl_xor(n[b], 16);  n[b] += __shfl_xor(n[b], 32);
  }
  int deg = s1 - s0;
  float inv = 1.f / (float)(deg > 0 ? deg : 1);
  if (lane < 8){
    #pragma unroll
    for (int b = 0; b < 8; ++b){
      #pragma unroll
      for (int k = 0; k < 4; ++k){
        int col = 32*lane + b + 8*k;
        int cnt = (int)((p[b] >> (8*k)) & 0xFF) - (int)((n[b] >> (8*k)) & 0xFF);
        av[col] = (float)cnt * inv;
      }
    }
  }
  const uint32_t* pr = packedH + (size_t)t * 16;
  for (int k = lane; k < 256; k += 64){
    int wq = k >> 5, b = k & 31;
    av[256 + k] = (float)((pr[wq] >> b) & 1) - (float)((pr[8 + wq] >> b) & 1);
  }
  __syncthreads();
  bool activeO = lane < 41;
  float acc = activeO ? bias[lane] : 0.f;
  for (int k = 0; k < 512; ++k){
    float bw = activeO ? Bcat2[k*41 + lane] : 0.f;
    acc += av[k] * bw;
  }
  float v = activeO ? acc : -INFINITY;
  float m = v;
  #pragma unroll
  for (int off = 32; off; off >>= 1) m = fmaxf(m, __shfl_xor(m, off));
  float e = activeO ? expf(v - m) : 0.f;
  float ssum = e;
  #pragma unroll
  for (int off = 32; off; off >>= 1) ssum += __shfl_xor(ssum, off);
  if (activeO) out[(size_t)t*41 + lane] = v - m - logf(ssum);
}

extern "C" void kernel_launch(void* const* d_in, const int* in_sizes, int n_in,
                              void* d_out, int out_size, void* d_ws, size_t ws_size,
                              hipStream_t stream){
  (void)n_in; (void)out_size; (void)ws_size;
  const float* x   = (const float*)d_in[0];
  const int*   ei1 = (const int*)d_in[1];
  const int*   ei2 = (const int*)d_in[2];
  const float* W1l = (const float*)d_in[5];
  const float* W1r = (const float*)d_in[6];
  const float* b1  = (const float*)d_in[7];
  const float* W2l = (const float*)d_in[8];
  const float* W2r = (const float*)d_in[9];
  const float* b2  = (const float*)d_in[10];
  float* out = (float*)d_out;

  const int FIN = 602, N1 = 11264, NB = 1024;
  const int N0 = in_sizes[0] / FIN;
  const int E1 = in_sizes[1] / 2;
  const int E2 = in_sizes[2] / 2;

  char* wsb = (char*)d_ws;
  size_t off = 0;
  auto carve = [&](size_t bytes)->void*{
    void* p = wsb + off;
    off = (off + bytes + 255) & ~(size_t)255;
    return p;
  };
  uint32_t* packedX = (uint32_t*)carve((size_t)N0*40*4);
  uint32_t* packedH = (uint32_t*)carve((size_t)N1*16*4);
  unsigned short* Sx = (unsigned short*)carve((size_t)N1*640*2);
  float* invdeg1 = (float*)carve((size_t)N1*4);
  unsigned short* bsgn = (unsigned short*)carve((size_t)256*1280*2);
  float* Bcat2 = (float*)carve((size_t)512*41*4);
  float* aL  = (float*)carve(256*4);
  float* aR  = (float*)carve(256*4);
  float* a2L = (float*)carve(64*4);
  float* a2R = (float*)carve(64*4);
  unsigned char* mask = (unsigned char*)carve((size_t)N0);
  int* degB  = (int*)carve((size_t)(N1+NB)*4);
  int* deg1  = degB;
  int* deg2  = degB + N1;
  int* rs1   = (int*)carve((size_t)(N1+1)*4);
  int* cur1  = (int*)carve((size_t)N1*4);
  int* esrc1 = (int*)carve((size_t)E1*4);
  int* rs2   = (int*)carve((size_t)(NB+1)*4);
  int* cur2  = (int*)carve((size_t)NB*4);
  int* esrc2 = (int*)carve((size_t)E2*4);

  const int maskBlocks = CDIV(N0, 256);
  const int cntBlocks  = CDIV(E1 + E2, 256);
  const int packBlocks = CDIV(N0, 8);      // 2 rows per wave, 4 waves per block
  const int bcatBlocks = CDIV(512*41, 256);

  // L0: alphas + zero degs + bsgn + mask init
  prep_all<<<1922 + maskBlocks, 256, 0, stream>>>(
      W1l, W1r, W2l, W2r, aL, aR, a2L, a2R, degB, N1 + NB, bsgn, mask, N0, N1);
  // L0.5: mark used rows + degree count
  mark_count<<<cntBlocks, 256, 0, stream>>>(ei1, ei1 + E1, E1, mask, deg1,
                                            ei2 + E2, E2, deg2);
  // L1: masked pack(x) 2 rows/wave + dual scans + Bcat2
  pack_scan_bcat<<<packBlocks + 2 + bcatBlocks, 256, 0, stream>>>(
      x, packedX, N0, mask, packBlocks,
      deg1, rs1, cur1, N1, deg2, rs2, cur2, NB,
      W2l, W2r, a2L, a2R, Bcat2);
  // L2: CSR fill
  fill_both<<<cntBlocks, 256, 0, stream>>>(ei1, ei1 + E1, E1, cur1, esrc1,
                                           ei2, ei2 + E2, E2, cur2, esrc2);
  // L3: layer-1 aggregate, 3 edges in flight
  aggregate_v3<<<N1, 64, 0, stream>>>(packedX, rs1, esrc1, Sx, invdeg1);
  // L4: layer-1 MFMA GEMM + bias + relu + fused norm_bin pack
  gemm1_fused<<<N1/32, 256, 0, stream>>>(Sx, packedX, bsgn, invdeg1, aL, aR, b1, packedH);
  // L5: fused layer-2 aggregate + GEMM + log_softmax
  agg_gemm2<<<NB, 64, 0, stream>>>(packedH, rs2, esrc2, Bcat2, b2, out);
}